// Round 7
// baseline (372.636 us; speedup 1.0000x reference)
//
#include <hip/hip_runtime.h>
#include <hip/hip_bf16.h>

// C3 partial connection via MFMA (fp16 in / fp32 acc), two-pass form.
// Pass 1 (xpack): fp32 planar x -> f16 channel-interleaved xp[b][row][148][8]
//   in d_ws (86 MB, L3-resident).
// Pass 2 (c3_conv): LDS-free conv. A-frag = one 16-B global load per (row,m):
//   lane (q, r): px = r+q (+4 for m=1), 8 channels contiguous. 120 MFMA/wave,
//   6-row register ring, wave-independent, nontemporal output stores.
// Fallback to R6 single-pass LDS kernel if ws_size is too small.

#define IH 142
#define IW 142
#define OH 138
#define OW 138
#define XPW 148           // padded px per packed row
#define WROWS 12          // output rows per wave
#define WSTRIDE 2592      // fallback kernel LDS halfs per wave

typedef _Float16 f16x8 __attribute__((ext_vector_type(8)));
typedef float f32x4 __attribute__((ext_vector_type(4)));
typedef float f32x2 __attribute__((ext_vector_type(2)));

// WIDX[oc][c] = src*64 + block-index, or -1. src 0=w3(6,3,5,5) 1=w4(9,4,5,5)
// 2=w6(1,6,5,5); weight elem = blk*25 + dy*5 + dx.
__device__ __constant__ const short WIDX16[16][6] = {
  {   0,    1,    2,   -1,   -1,   -1},   // oc0  {0,1,2}
  {  -1,    3,    4,    5,   -1,   -1},   // oc1  {1,2,3}
  {  -1,   -1,    6,    7,    8,   -1},   // oc2  {2,3,4}
  {  -1,   -1,   -1,    9,   10,   11},   // oc3  {3,4,5}
  {  12,   -1,   -1,   -1,   13,   14},   // oc4  {0,4,5}
  {  15,   16,   -1,   -1,   -1,   17},   // oc5  {0,1,5}
  {64+0, 64+1, 64+2, 64+3,   -1,   -1},   // oc6  {0,1,2,3}
  {  -1, 64+4, 64+5, 64+6, 64+7,   -1},   // oc7  {1,2,3,4}
  {  -1,   -1, 64+8, 64+9, 64+10, 64+11}, // oc8  {2,3,4,5}
  {64+12,  -1,   -1, 64+13, 64+14, 64+15},// oc9  {0,3,4,5}
  {64+16, 64+17, -1,   -1, 64+18, 64+19}, // oc10 {0,1,4,5}
  {64+20, 64+21, 64+22, -1,  -1, 64+23},  // oc11 {0,1,2,5}
  {64+24, 64+25, -1, 64+26, 64+27,  -1},  // oc12 {0,1,3,4}
  {  -1, 64+28, 64+29, -1, 64+30, 64+31}, // oc13 {1,2,4,5}
  {64+32,  -1, 64+33, 64+34, -1, 64+35},  // oc14 {0,2,3,5}
  {128+0, 128+1, 128+2, 128+3, 128+4, 128+5}, // oc15 {0..5}
};

// prep: per-lane pre-swizzled B fragments, 5 dy x 2 m x 64 lanes x 8 halfs.
// k = m*32 + q*8 + j -> dx = k>>3, c = k&7; zero unless dx<5 && c<6 && consumed.
__global__ void wprep_kernel(const float* __restrict__ w3, const float* __restrict__ w4,
                             const float* __restrict__ w6, _Float16* __restrict__ tab) {
  int t = blockIdx.x * 256 + threadIdx.x;
  if (t >= 5120) return;
  int j = t & 7, lane = (t >> 3) & 63, dm = t >> 9;
  int dy = dm >> 1, m = dm & 1;
  int q = lane >> 4, oc = lane & 15;
  int k = m * 32 + q * 8 + j;
  int dx = k >> 3, c = k & 7;
  float v = 0.f;
  if (c < 6 && dx < 5) {
    int e = WIDX16[oc][c];
    if (e >= 0) {
      int src = e >> 6, blk = e & 63;
      const float* wp = (src == 0) ? w3 : (src == 1) ? w4 : w6;
      v = wp[blk * 25 + dy * 5 + dx];
    }
  }
  tab[t] = (_Float16)v;
}

// ---- pass 1: planar fp32 -> channel-interleaved f16 [b][row][XPW][8] ----
__global__ __launch_bounds__(256)
void xpack_kernel(const float* __restrict__ x, _Float16* __restrict__ xp) {
  const int idx = blockIdx.x * 256 + threadIdx.x;
  const int total = 256 * IH * 37;          // 37 quads of 4 px cover XPW=148
  if (idx >= total) return;
  const int b   = idx / (IH * 37);
  const int rem = idx - b * (IH * 37);
  const int row = rem / 37;
  const int qd  = rem - row * 37;
  const int col0 = qd * 4;

  const float* xb = x + ((size_t)b * 6 * IH + row) * IW;
  float v[6][4];
  if (qd < 35) {                            // cols <= 139+..143? col0+3 <= 139: safe float4
    #pragma unroll
    for (int c = 0; c < 6; ++c) {
      const float4 f = *(const float4*)(xb + (size_t)c * IH * IW + col0);
      v[c][0] = f.x; v[c][1] = f.y; v[c][2] = f.z; v[c][3] = f.w;
    }
  } else {                                  // cols 140..147: clamp to 141 (pad px meet zero weights)
    #pragma unroll
    for (int c = 0; c < 6; ++c)
      #pragma unroll
      for (int p = 0; p < 4; ++p)
        v[c][p] = xb[(size_t)c * IH * IW + min(col0 + p, IW - 1)];
  }

  _Float16* dst = xp + (((size_t)b * IH + row) * XPW + col0) * 8;
  #pragma unroll
  for (int p = 0; p < 4; ++p) {
    f16x8 h;
    #pragma unroll
    for (int c = 0; c < 6; ++c) h[c] = (_Float16)v[c][p];
    h[6] = (_Float16)0.f; h[7] = (_Float16)0.f;
    *(f16x8*)(dst + p * 8) = h;
  }
}

__device__ __forceinline__ float act(float y) {
  const float TS = 1.9235933878519512f;  // 2*(2/3)*log2(e)
  const float e = __builtin_amdgcn_exp2f(y * TS);
  return fmaf(-2.f * 1.7159f, __builtin_amdgcn_rcpf(e + 1.f), 1.7159f);
}

__device__ __forceinline__ void nt_store2(float* p, float a, float b) {
  f32x2 v = {a, b};
  __builtin_nontemporal_store(v, (f32x2*)p);
}

// ---- pass 2: LDS-free MFMA conv ----
// Block: 256 threads = 4 independent waves; wave w -> rows y0+w*12..+11, 16 px.
__global__ __launch_bounds__(256, 4)
void c3_conv(const _Float16* __restrict__ xp,
             const float* __restrict__ b3, const float* __restrict__ b4,
             const float* __restrict__ b6, const _Float16* __restrict__ tab,
             float* __restrict__ out) {
  const int tid  = threadIdx.x;
  const int lane = tid & 63;
  const int w    = tid >> 6;
  const int b    = blockIdx.z;
  const int x0   = min((int)blockIdx.x * 16, OW - 16);  // {0,16,...,112,122}
  const int y0   = min((int)blockIdx.y * 48, OH - 48);  // {0,48,90}
  const int ry0  = y0 + w * WROWS;

  const int ocl = lane & 15;   // A row / B col / C col
  const int q   = lane >> 4;

  // B fragments (10 x 16B coalesced)
  f16x8 Bf[5][2];
  #pragma unroll
  for (int dy = 0; dy < 5; ++dy)
    #pragma unroll
    for (int m = 0; m < 2; ++m)
      Bf[dy][m] = *(const f16x8*)(tab + ((size_t)((dy * 2 + m) * 64 + lane)) * 8);

  const float bv = (ocl < 6) ? b3[ocl] : (ocl < 15) ? b4[ocl - 6] : b6[0];

  // A-frag base: px = x0 + ocl + q (m=1: +4 px = +32 halfs); row r at + r*XPW*8
  const _Float16* __restrict__ ap =
      xp + (((size_t)b * IH + ry0) * XPW + x0 + ocl + q) * 8;

  f16x8 W6[6][2];
  #pragma unroll
  for (int i = 0; i < 6; ++i) {
    W6[i][0] = *(const f16x8*)(ap + (size_t)i * (XPW * 8));
    W6[i][1] = *(const f16x8*)(ap + (size_t)i * (XPW * 8) + 32);
  }

  const size_t obase = ((size_t)b * 16 + ocl) * OH;
  #pragma unroll
  for (int r = 0; r < WROWS; r += 2) {
    f32x4 C0 = {bv, bv, bv, bv};
    f32x4 C1 = {bv, bv, bv, bv};
    #pragma unroll
    for (int dy = 0; dy < 5; ++dy) {
      const int i0 = (r + dy) % 6;       // compile-time after unroll
      const int i1 = (r + 1 + dy) % 6;
      C0 = __builtin_amdgcn_mfma_f32_16x16x32_f16(W6[i0][0], Bf[dy][0], C0, 0, 0, 0);
      C1 = __builtin_amdgcn_mfma_f32_16x16x32_f16(W6[i1][0], Bf[dy][0], C1, 0, 0, 0);
      C0 = __builtin_amdgcn_mfma_f32_16x16x32_f16(W6[i0][1], Bf[dy][1], C0, 0, 0, 0);
      C1 = __builtin_amdgcn_mfma_f32_16x16x32_f16(W6[i1][1], Bf[dy][1], C1, 0, 0, 0);
    }
    if (r + 2 < WROWS) {  // slide: rows r+6, r+7
      W6[r % 6][0]       = *(const f16x8*)(ap + (size_t)(r + 6) * (XPW * 8));
      W6[r % 6][1]       = *(const f16x8*)(ap + (size_t)(r + 6) * (XPW * 8) + 32);
      W6[(r + 1) % 6][0] = *(const f16x8*)(ap + (size_t)(r + 7) * (XPW * 8));
      W6[(r + 1) % 6][1] = *(const f16x8*)(ap + (size_t)(r + 7) * (XPW * 8) + 32);
    }
    {
      float* p0 = out + (obase + (ry0 + r)) * OW + x0 + q * 4;
      float* p1 = out + (obase + (ry0 + r + 1)) * OW + x0 + q * 4;
      nt_store2(p0,     act(C0[0]), act(C0[1]));
      nt_store2(p0 + 2, act(C0[2]), act(C0[3]));
      nt_store2(p1,     act(C1[0]), act(C1[1]));
      nt_store2(p1 + 2, act(C1[2]), act(C1[3]));
    }
  }
}

// ---- fallback (R6): single-pass, wave-private LDS staging ----
__device__ __forceinline__ unsigned int pkh(float a, float b) {
  _Float16 ha = (_Float16)a, hb = (_Float16)b;
  unsigned short ua = __builtin_bit_cast(unsigned short, ha);
  unsigned short ub = __builtin_bit_cast(unsigned short, hb);
  return (unsigned int)ua | ((unsigned int)ub << 16);
}

__global__ __launch_bounds__(256, 4)
void c3_mfma_lds(const float* __restrict__ x,
                 const float* __restrict__ b3, const float* __restrict__ b4,
                 const float* __restrict__ b6, const _Float16* __restrict__ tab,
                 float* __restrict__ out) {
  __shared__ __attribute__((aligned(16))) _Float16 sh[4 * WSTRIDE];

  const int tid  = threadIdx.x;
  const int lane = tid & 63;
  const int w    = tid >> 6;
  const int b    = blockIdx.z;
  const int x0   = min((int)blockIdx.x * 16, OW - 16);
  const int y0   = min((int)blockIdx.y * 48, OH - 48);
  const int ry0  = y0 + w * WROWS;
  const int ocl = lane & 15;
  const int q   = lane >> 4;

  f16x8 Bf[5][2];
  #pragma unroll
  for (int dy = 0; dy < 5; ++dy)
    #pragma unroll
    for (int m = 0; m < 2; ++m)
      Bf[dy][m] = *(const f16x8*)(tab + ((size_t)((dy * 2 + m) * 64 + lane)) * 8);

  const float bv = (ocl < 6) ? b3[ocl] : (ocl < 15) ? b4[ocl - 6] : b6[0];

  _Float16* __restrict__ shw = sh + w * WSTRIDE;
  if (lane < 16) ((unsigned int*)shw)[1280 + lane] = 0u;

  const float* xb = x + (size_t)b * 6 * IH * IW;
  #pragma unroll
  for (int it = 0; it < 10; ++it) {
    const int idx = it * 64 + lane;
    const int c2  = idx / 160;
    const int rem = idx - c2 * 160;
    const int row = rem / 10;
    const int px2 = rem - row * 10;
    const int ha  = row * 160 + px2 * 16 + c2 * 2;
    if (c2 < 3) {
      const float* pa = xb + ((size_t)(2 * c2) * IH + (ry0 + row)) * IW + x0 + 2 * px2;
      const float* pb = pa + (size_t)IH * IW;
      const float2 va = *(const float2*)pa;
      const float2 vb = *(const float2*)pb;
      *(unsigned int*)&shw[ha]     = pkh(va.x, vb.x);
      *(unsigned int*)&shw[ha + 8] = pkh(va.y, vb.y);
    } else {
      *(unsigned int*)&shw[ha]     = 0u;
      *(unsigned int*)&shw[ha + 8] = 0u;
    }
  }
  asm volatile("s_waitcnt lgkmcnt(0)" ::: "memory");

  const int voff = (ocl + q) * 8;
  f16x8 W6[6][2];
  #pragma unroll
  for (int i = 0; i < 6; ++i) {
    W6[i][0] = *(const f16x8*)&shw[i * 160 + voff];
    W6[i][1] = *(const f16x8*)&shw[i * 160 + voff + 32];
  }

  const size_t obase = ((size_t)b * 16 + ocl) * OH;
  #pragma unroll
  for (int r = 0; r < WROWS; r += 2) {
    f32x4 C0 = {bv, bv, bv, bv};
    f32x4 C1 = {bv, bv, bv, bv};
    #pragma unroll
    for (int dy = 0; dy < 5; ++dy) {
      const int i0 = (r + dy) % 6;
      const int i1 = (r + 1 + dy) % 6;
      C0 = __builtin_amdgcn_mfma_f32_16x16x32_f16(W6[i0][0], Bf[dy][0], C0, 0, 0, 0);
      C1 = __builtin_amdgcn_mfma_f32_16x16x32_f16(W6[i1][0], Bf[dy][0], C1, 0, 0, 0);
      C0 = __builtin_amdgcn_mfma_f32_16x16x32_f16(W6[i0][1], Bf[dy][1], C0, 0, 0, 0);
      C1 = __builtin_amdgcn_mfma_f32_16x16x32_f16(W6[i1][1], Bf[dy][1], C1, 0, 0, 0);
    }
    if (r + 2 < WROWS) {
      W6[r % 6][0]       = *(const f16x8*)&shw[(r + 6) * 160 + voff];
      W6[r % 6][1]       = *(const f16x8*)&shw[(r + 6) * 160 + voff + 32];
      W6[(r + 1) % 6][0] = *(const f16x8*)&shw[(r + 7) * 160 + voff];
      W6[(r + 1) % 6][1] = *(const f16x8*)&shw[(r + 7) * 160 + voff + 32];
    }
    {
      float* p0 = out + (obase + (ry0 + r)) * OW + x0 + q * 4;
      float* p1 = out + (obase + (ry0 + r + 1)) * OW + x0 + q * 4;
      *(float2*)p0       = make_float2(act(C0[0]), act(C0[1]));
      *(float2*)(p0 + 2) = make_float2(act(C0[2]), act(C0[3]));
      *(float2*)p1       = make_float2(act(C1[0]), act(C1[1]));
      *(float2*)(p1 + 2) = make_float2(act(C1[2]), act(C1[3]));
    }
  }
}

extern "C" void kernel_launch(void* const* d_in, const int* in_sizes, int n_in,
                              void* d_out, int out_size, void* d_ws, size_t ws_size,
                              hipStream_t stream) {
  const float* x  = (const float*)d_in[0];
  const float* w3 = (const float*)d_in[1];
  const float* b3 = (const float*)d_in[2];
  const float* w4 = (const float*)d_in[3];
  const float* b4 = (const float*)d_in[4];
  const float* w6 = (const float*)d_in[5];
  const float* b6 = (const float*)d_in[6];
  float* out = (float*)d_out;

  _Float16* tab = (_Float16*)d_ws;                       // 10 KiB
  _Float16* xp  = (_Float16*)((char*)d_ws + 16384);      // 86 MB packed input
  const size_t need = 16384 + (size_t)256 * IH * XPW * 8 * sizeof(_Float16);

  hipLaunchKernelGGL(wprep_kernel, dim3(20), dim3(256), 0, stream, w3, w4, w6, tab);

  dim3 grid(9, 3, 256);
  if (ws_size >= need) {
    const int total = 256 * IH * 37;
    hipLaunchKernelGGL(xpack_kernel, dim3((total + 255) / 256), dim3(256), 0, stream, x, xp);
    hipLaunchKernelGGL(c3_conv, grid, dim3(256), 0, stream, xp, b3, b4, b6, tab, out);
  } else {
    hipLaunchKernelGGL(c3_mfma_lds, grid, dim3(256), 0, stream, x, b3, b4, b6, tab, out);
  }
}

// Round 8
// 232.398 us; speedup vs baseline: 1.6034x; 1.6034x over previous
//
#include <hip/hip_runtime.h>
#include <hip/hip_bf16.h>

// C3 partial connection via MFMA (fp16 in / fp32 acc), deep-pipelined one-pass.
// y = conv5x5(channel-subsets) + bias; out = 1.7159*tanh(2/3*y).
// M = 16 px, N = 16 oc, K = dx*8 + c (c pad 6->8); 2 mfma_16x16x32_f16 per
// (row, dy) (m=0: dx0..3, m=1: dx4).
//
// R8: each wave owns 16 px x 48 output rows and runs a steady-state pipeline
// per output-row pair r:
//   issue global pf loads rows r+10,r+11 -> regs          (consumed next pair)
//   20 MFMA (6-row register ring) + act + stores
//   LDS slide-read rows r+6,r+7 into the register ring
//   pack + ds_write rows r+8,r+9 (pf from LAST pair) into 12-row LDS ring
// Global-load -> first-MFMA-use distance = 4 pairs (~2000 cyc): HBM latency
// hidden (T14). No __syncthreads anywhere: waves fully independent,
// wave-private LDS ring, in-wave lgkm ordering only.

#define IH 142
#define IW 142
#define OH 138
#define OW 138
#define RING 12                      // input-row slots per wave
#define RHALF 160                    // halfs per row slot (20 px * 8 ch)
#define WV_HALFS (RING * RHALF + 32) // + overflow tail pad

typedef _Float16 f16x8 __attribute__((ext_vector_type(8)));
typedef float f32x4 __attribute__((ext_vector_type(4)));

// WIDX[oc][c] = src*64 + block-index, or -1. src 0=w3(6,3,5,5) 1=w4(9,4,5,5)
// 2=w6(1,6,5,5); weight elem = blk*25 + dy*5 + dx.
__device__ __constant__ const short WIDX16[16][6] = {
  {   0,    1,    2,   -1,   -1,   -1},   // oc0  {0,1,2}
  {  -1,    3,    4,    5,   -1,   -1},   // oc1  {1,2,3}
  {  -1,   -1,    6,    7,    8,   -1},   // oc2  {2,3,4}
  {  -1,   -1,   -1,    9,   10,   11},   // oc3  {3,4,5}
  {  12,   -1,   -1,   -1,   13,   14},   // oc4  {0,4,5}
  {  15,   16,   -1,   -1,   -1,   17},   // oc5  {0,1,5}
  {64+0, 64+1, 64+2, 64+3,   -1,   -1},   // oc6  {0,1,2,3}
  {  -1, 64+4, 64+5, 64+6, 64+7,   -1},   // oc7  {1,2,3,4}
  {  -1,   -1, 64+8, 64+9, 64+10, 64+11}, // oc8  {2,3,4,5}
  {64+12,  -1,   -1, 64+13, 64+14, 64+15},// oc9  {0,3,4,5}
  {64+16, 64+17, -1,   -1, 64+18, 64+19}, // oc10 {0,1,4,5}
  {64+20, 64+21, 64+22, -1,  -1, 64+23},  // oc11 {0,1,2,5}
  {64+24, 64+25, -1, 64+26, 64+27,  -1},  // oc12 {0,1,3,4}
  {  -1, 64+28, 64+29, -1, 64+30, 64+31}, // oc13 {1,2,4,5}
  {64+32,  -1, 64+33, 64+34, -1, 64+35},  // oc14 {0,2,3,5}
  {128+0, 128+1, 128+2, 128+3, 128+4, 128+5}, // oc15 {0..5}
};

// prep: per-lane pre-swizzled B fragments, 5 dy x 2 m x 64 lanes x 8 halfs.
// k = m*32 + q*8 + j -> dx = k>>3, c = k&7; zero unless dx<5 && c<6 && consumed.
__global__ void wprep_kernel(const float* __restrict__ w3, const float* __restrict__ w4,
                             const float* __restrict__ w6, _Float16* __restrict__ tab) {
  int t = blockIdx.x * 256 + threadIdx.x;
  if (t >= 5120) return;
  int j = t & 7, lane = (t >> 3) & 63, dm = t >> 9;
  int dy = dm >> 1, m = dm & 1;
  int q = lane >> 4, oc = lane & 15;
  int k = m * 32 + q * 8 + j;
  int dx = k >> 3, c = k & 7;
  float v = 0.f;
  if (c < 6 && dx < 5) {
    int e = WIDX16[oc][c];
    if (e >= 0) {
      int src = e >> 6, blk = e & 63;
      const float* wp = (src == 0) ? w3 : (src == 1) ? w4 : w6;
      v = wp[blk * 25 + dy * 5 + dx];
    }
  }
  tab[t] = (_Float16)v;
}

__device__ __forceinline__ unsigned int pkh(float a, float b) {
  _Float16 ha = (_Float16)a, hb = (_Float16)b;
  unsigned short ua = __builtin_bit_cast(unsigned short, ha);
  unsigned short ub = __builtin_bit_cast(unsigned short, hb);
  return (unsigned int)ua | ((unsigned int)ub << 16);
}

__device__ __forceinline__ float act(float y) {
  const float TS = 1.9235933878519512f;  // 2*(2/3)*log2(e)
  const float e = __builtin_amdgcn_exp2f(y * TS);
  // A*tanh(S*y) = A - 2A/(exp2(TS*y)+1); saturates correctly at +/-inf.
  return fmaf(-2.f * 1.7159f, __builtin_amdgcn_rcpf(e + 1.f), 1.7159f);
}

// Block: 192 threads = 3 independent waves (y-slabs {0,48,90}); 16 px wide.
// Grid: (9 x-tiles shifted, 1, 256 images).
__global__ __launch_bounds__(192, 4)
void c3_pipe(const float* __restrict__ x,
             const float* __restrict__ b3, const float* __restrict__ b4,
             const float* __restrict__ b6, const _Float16* __restrict__ tab,
             float* __restrict__ out) {
  __shared__ __attribute__((aligned(16))) _Float16 sh[3 * WV_HALFS];  // 11712 B

  const int tid  = threadIdx.x;
  const int lane = tid & 63;
  const int w    = tid >> 6;
  const int b    = blockIdx.z;
  const int x0   = min((int)blockIdx.x * 16, OW - 16);  // {0,16,...,112,122}
  const int wy0  = min(w * 48, OH - 48);                // {0,48,90}

  const int ocl = lane & 15;   // A row-group / B col / C col (output channel)
  const int q   = lane >> 4;

  _Float16* __restrict__ shw = sh + w * WV_HALFS;
  unsigned int* __restrict__ shu = (unsigned int*)shw;

  // ---- zero own ring + pads (976 dwords): kills NaN into zero-weight K ----
  #pragma unroll
  for (int i = 0; i < 16; ++i) {
    const int idx = i * 64 + lane;
    if (idx < WV_HALFS / 2) shu[idx] = 0u;
  }

  // ---- B fragments (10 x 16B coalesced; L2-hot after first waves) ----
  f16x8 Bf[5][2];
  #pragma unroll
  for (int dy = 0; dy < 5; ++dy)
    #pragma unroll
    for (int m = 0; m < 2; ++m)
      Bf[dy][m] = *(const f16x8*)(tab + ((size_t)((dy * 2 + m) * 64 + lane)) * 8);

  const float bv = (ocl < 6) ? b3[ocl] : (ocl < 15) ? b4[ocl - 6] : b6[0];

  // ---- stage-lane decode: item = (c2, rowpar, px2); lanes 60..63 idle ----
  const int c2     = lane / 20;
  const int rem2   = lane - 20 * c2;
  const int rowpar = rem2 / 10;
  const int px2    = rem2 - 10 * rowpar;
  const bool active = (c2 < 3);
  const float* __restrict__ xpl =
      x + (size_t)b * 6 * IH * IW + (size_t)min(2 * c2, 4) * (IH * IW);
  const int colo = x0 + 2 * px2;                 // even -> 8B-aligned loads
  const size_t PLANE = (size_t)IH * IW;

  // ---- prime: stage input rows 0..7 (max load ILP: all loads, then packs) ----
  float2 sva[4], svb[4];
  #pragma unroll
  for (int s = 0; s < 4; ++s) {
    if (active) {
      const int grow = wy0 + 2 * s + rowpar;     // <= 97, in-bounds
      sva[s] = *(const float2*)(xpl + (size_t)grow * IW + colo);
      svb[s] = *(const float2*)(xpl + PLANE + (size_t)grow * IW + colo);
    }
  }
  #pragma unroll
  for (int s = 0; s < 4; ++s) {
    if (active) {
      const int slot = 2 * s + rowpar;           // rows 0..7 -> slots 0..7
      shu[slot * 80 + px2 * 8 + c2]     = pkh(sva[s].x, svb[s].x);
      shu[slot * 80 + px2 * 8 + c2 + 4] = pkh(sva[s].y, svb[s].y);
    }
  }

  // ---- prime pf: rows 8,9 -> buf1 (consumed by pair kk=0) ----
  float2 pA0, pB0, pA1, pB1;
  if (active) {
    const int grow = wy0 + 8 + rowpar;
    pA1 = *(const float2*)(xpl + (size_t)grow * IW + colo);
    pB1 = *(const float2*)(xpl + PLANE + (size_t)grow * IW + colo);
  }

  // ---- fill register ring with rows 0..5 ----
  const int voff = (ocl + q) * 8;                // halfs; +32 for m=1 (dx+4)
  f16x8 W6[6][2];
  #pragma unroll
  for (int i = 0; i < 6; ++i) {
    W6[i][0] = *(const f16x8*)&shw[i * RHALF + voff];
    W6[i][1] = *(const f16x8*)&shw[i * RHALF + voff + 32];
  }

  const size_t obase = ((size_t)b * 16 + ocl) * OH;

  // ---- main: 4 chunks x 6 pairs = 48 output rows; all ring indices static ----
  #pragma unroll 1
  for (int ch4 = 0; ch4 < 4; ++ch4) {
    const int rb = ch4 * 12;
    #pragma unroll
    for (int kk = 0; kk < 6; ++kk) {
      const int r = rb + 2 * kk;
      // 1. pf issue rows r+10, r+11 -> buf (kk&1)
      float2 nA, nB;
      if (active) {
        const int grow = min(wy0 + r + 10 + rowpar, IH - 1);  // tail clamp
        nA = *(const float2*)(xpl + (size_t)grow * IW + colo);
        nB = *(const float2*)(xpl + PLANE + (size_t)grow * IW + colo);
      }
      if ((kk & 1) == 0) { pA0 = nA; pB0 = nB; } else { pA1 = nA; pB1 = nB; }

      // 2. MFMA pair (rows r, r+1 need input rows r..r+5)
      f32x4 C0 = {bv, bv, bv, bv};
      f32x4 C1 = {bv, bv, bv, bv};
      #pragma unroll
      for (int dy = 0; dy < 5; ++dy) {
        const int i0 = (2 * kk + dy) % 6;        // compile-time after unroll
        const int i1 = (2 * kk + 1 + dy) % 6;
        C0 = __builtin_amdgcn_mfma_f32_16x16x32_f16(W6[i0][0], Bf[dy][0], C0, 0, 0, 0);
        C1 = __builtin_amdgcn_mfma_f32_16x16x32_f16(W6[i1][0], Bf[dy][0], C1, 0, 0, 0);
        C0 = __builtin_amdgcn_mfma_f32_16x16x32_f16(W6[i0][1], Bf[dy][1], C0, 0, 0, 0);
        C1 = __builtin_amdgcn_mfma_f32_16x16x32_f16(W6[i1][1], Bf[dy][1], C1, 0, 0, 0);
      }

      // 3. epilogue + stores (always in-bounds; shifted tiles overlap-consistent)
      {
        float* p0 = out + (obase + (wy0 + r)) * OW + x0 + q * 4;
        float* p1 = p0 + OW;
        *(float2*)p0       = make_float2(act(C0[0]), act(C0[1]));
        *(float2*)(p0 + 2) = make_float2(act(C0[2]), act(C0[3]));
        *(float2*)p1       = make_float2(act(C1[0]), act(C1[1]));
        *(float2*)(p1 + 2) = make_float2(act(C1[2]), act(C1[3]));
      }

      // 4. slide register ring: rows r+6, r+7 (written to LDS >= 1 pair ago)
      {
        const int s0 = (2 * kk + 6) % 12, s1 = (2 * kk + 7) % 12;
        const int w0 = (2 * kk) % 6,      w1 = (2 * kk + 1) % 6;
        W6[w0][0] = *(const f16x8*)&shw[s0 * RHALF + voff];
        W6[w0][1] = *(const f16x8*)&shw[s0 * RHALF + voff + 32];
        W6[w1][0] = *(const f16x8*)&shw[s1 * RHALF + voff];
        W6[w1][1] = *(const f16x8*)&shw[s1 * RHALF + voff + 32];
      }

      // 5. consume pf issued LAST pair: pack + ds_write rows r+8, r+9
      if (active) {
        const float2 uA = ((kk & 1) == 0) ? pA1 : pA0;
        const float2 uB = ((kk & 1) == 0) ? pB1 : pB0;
        const int slot = (2 * kk + 8 + rowpar) % 12;
        shu[slot * 80 + px2 * 8 + c2]     = pkh(uA.x, uB.x);
        shu[slot * 80 + px2 * 8 + c2 + 4] = pkh(uA.y, uB.y);
      }
    }
  }
}

extern "C" void kernel_launch(void* const* d_in, const int* in_sizes, int n_in,
                              void* d_out, int out_size, void* d_ws, size_t ws_size,
                              hipStream_t stream) {
  const float* x  = (const float*)d_in[0];
  const float* w3 = (const float*)d_in[1];
  const float* b3 = (const float*)d_in[2];
  const float* w4 = (const float*)d_in[3];
  const float* b4 = (const float*)d_in[4];
  const float* w6 = (const float*)d_in[5];
  const float* b6 = (const float*)d_in[6];
  float* out = (float*)d_out;
  _Float16* tab = (_Float16*)d_ws;  // 5120 halfs = 10 KiB

  hipLaunchKernelGGL(wprep_kernel, dim3(20), dim3(256), 0, stream, w3, w4, w6, tab);

  dim3 grid(9, 1, 256);   // x-tiles (16 px, last shifted), 1, batch
  hipLaunchKernelGGL(c3_pipe, grid, dim3(192), 0, stream, x, b3, b4, b6, tab, out);
}

// Round 9
// 174.981 us; speedup vs baseline: 2.1296x; 1.3281x over previous
//
#include <hip/hip_runtime.h>
#include <hip/hip_bf16.h>

// C3 partial connection via MFMA (fp16 in / fp32 acc), wave-independent form.
// y = conv5x5(channel-subsets) + bias; out = 1.7159*tanh(2/3*y).
// M = 16 consecutive x-pixels, N = 16 output channels, K = dx*8 + c (c pad 6->8),
// two mfma_f32_16x16x32_f16 per (row, dy): m=0 dx0..3, m=1 dx4 (rest zero-wt).
//
// R9 = R6 + chunked XCD blockIdx swizzle. Adjacent x-tiles write the two 64B
// halves of the same 128B output lines; default round-robin puts them on
// DIFFERENT XCDs (non-coherent L2s) -> every line written to HBM twice
// (WRITE 455MB vs 312 ideal) + RFO fills. Chunked remap (hwid%8 -> XCD owns a
// contiguous tile run, x fastest) merges line halves in one L2 and makes halo
// re-reads L2 hits.

#define IH 142
#define IW 142
#define OH 138
#define OW 138
#define WROWS 12        // output rows per wave
#define WSTRIDE 2592    // halfs per wave LDS region: 16 rows * 160 + 32 pad
#define NTILE_X 9
#define NTILE_Y 3
#define NWG (NTILE_X * NTILE_Y * 256)   // 6912, divisible by 8
#define CPX (NWG / 8)                   // 864 tiles per XCD

typedef _Float16 f16x8 __attribute__((ext_vector_type(8)));
typedef float f32x4 __attribute__((ext_vector_type(4)));

// WIDX[oc][c] = src*64 + block-index, or -1. src 0=w3(6,3,5,5) 1=w4(9,4,5,5)
// 2=w6(1,6,5,5); weight elem = blk*25 + dy*5 + dx.
__device__ __constant__ const short WIDX16[16][6] = {
  {   0,    1,    2,   -1,   -1,   -1},   // oc0  {0,1,2}
  {  -1,    3,    4,    5,   -1,   -1},   // oc1  {1,2,3}
  {  -1,   -1,    6,    7,    8,   -1},   // oc2  {2,3,4}
  {  -1,   -1,   -1,    9,   10,   11},   // oc3  {3,4,5}
  {  12,   -1,   -1,   -1,   13,   14},   // oc4  {0,4,5}
  {  15,   16,   -1,   -1,   -1,   17},   // oc5  {0,1,5}
  {64+0, 64+1, 64+2, 64+3,   -1,   -1},   // oc6  {0,1,2,3}
  {  -1, 64+4, 64+5, 64+6, 64+7,   -1},   // oc7  {1,2,3,4}
  {  -1,   -1, 64+8, 64+9, 64+10, 64+11}, // oc8  {2,3,4,5}
  {64+12,  -1,   -1, 64+13, 64+14, 64+15},// oc9  {0,3,4,5}
  {64+16, 64+17, -1,   -1, 64+18, 64+19}, // oc10 {0,1,4,5}
  {64+20, 64+21, 64+22, -1,  -1, 64+23},  // oc11 {0,1,2,5}
  {64+24, 64+25, -1, 64+26, 64+27,  -1},  // oc12 {0,1,3,4}
  {  -1, 64+28, 64+29, -1, 64+30, 64+31}, // oc13 {1,2,4,5}
  {64+32,  -1, 64+33, 64+34, -1, 64+35},  // oc14 {0,2,3,5}
  {128+0, 128+1, 128+2, 128+3, 128+4, 128+5}, // oc15 {0..5}
};

// prep: per-lane pre-swizzled B fragments, 5 dy x 2 m x 64 lanes x 8 halfs.
__global__ void wprep_kernel(const float* __restrict__ w3, const float* __restrict__ w4,
                             const float* __restrict__ w6, _Float16* __restrict__ tab) {
  int t = blockIdx.x * 256 + threadIdx.x;
  if (t >= 5120) return;
  int j = t & 7, lane = (t >> 3) & 63, dm = t >> 9;
  int dy = dm >> 1, m = dm & 1;
  int q = lane >> 4, oc = lane & 15;
  int k = m * 32 + q * 8 + j;
  int dx = k >> 3, c = k & 7;
  float v = 0.f;
  if (c < 6 && dx < 5) {
    int e = WIDX16[oc][c];
    if (e >= 0) {
      int src = e >> 6, blk = e & 63;
      const float* wp = (src == 0) ? w3 : (src == 1) ? w4 : w6;
      v = wp[blk * 25 + dy * 5 + dx];
    }
  }
  tab[t] = (_Float16)v;
}

__device__ __forceinline__ unsigned int pkh(float a, float b) {
  _Float16 ha = (_Float16)a, hb = (_Float16)b;
  unsigned short ua = __builtin_bit_cast(unsigned short, ha);
  unsigned short ub = __builtin_bit_cast(unsigned short, hb);
  return (unsigned int)ua | ((unsigned int)ub << 16);
}

__device__ __forceinline__ float act(float y) {
  const float TS = 1.9235933878519512f;  // 2*(2/3)*log2(e)
  const float e = __builtin_amdgcn_exp2f(y * TS);
  return fmaf(-2.f * 1.7159f, __builtin_amdgcn_rcpf(e + 1.f), 1.7159f);
}

// Block: 256 threads = 4 independent waves; wave w -> output rows y0+w*12..+11,
// 16 px wide. Logical grid: (9 x-tiles shifted, 3 y-tiles {0,48,90}, 256 images),
// XCD-chunk-swizzled from the 1D hardware dispatch order.
__global__ __launch_bounds__(256, 4)
void c3_mfma(const float* __restrict__ x,
             const float* __restrict__ b3, const float* __restrict__ b4,
             const float* __restrict__ b6, const _Float16* __restrict__ tab,
             float* __restrict__ out) {
  __shared__ __attribute__((aligned(16))) _Float16 sh[4 * WSTRIDE];  // 20736 B

  const int tid  = threadIdx.x;
  const int lane = tid & 63;
  const int w    = tid >> 6;

  // ---- chunked XCD swizzle: hwid%8 = XCD -> give each XCD a contiguous
  // run of tiles (x fastest => adjacent x-tiles same XCD, close in time) ----
  const int hwid = (int)blockIdx.x + NTILE_X * ((int)blockIdx.y + NTILE_Y * (int)blockIdx.z);
  const int swz  = (hwid & 7) * CPX + (hwid >> 3);
  const int tx   = swz % NTILE_X;
  const int t2   = swz / NTILE_X;
  const int ty   = t2 % NTILE_Y;
  const int b    = t2 / NTILE_Y;

  const int x0   = min(tx * 16, OW - 16);  // {0,16,...,112,122}
  const int y0   = min(ty * 48, OH - 48);  // {0,48,90}
  const int ry0  = y0 + w * WROWS;         // wave's first row

  const int ocl = lane & 15;
  const int q   = lane >> 4;

  // ---- B fragments (independent, issue first) ----
  f16x8 Bf[5][2];
  #pragma unroll
  for (int dy = 0; dy < 5; ++dy)
    #pragma unroll
    for (int m = 0; m < 2; ++m)
      Bf[dy][m] = *(const f16x8*)(tab + ((size_t)((dy * 2 + m) * 64 + lane)) * 8);

  const float bv = (ocl < 6) ? b3[ocl] : (ocl < 15) ? b4[ocl - 6] : b6[0];

  // ---- wave-private staging: 16 rows x 20 px x 8 ch halfs ----
  _Float16* __restrict__ shw = sh + w * WSTRIDE;
  // zero own 32-half tail pad (read by m=1 frags of last rows, x zero-weight)
  if (lane < 16) ((unsigned int*)shw)[1280 + lane] = 0u;

  const float* xb = x + (size_t)b * 6 * IH * IW;
  #pragma unroll
  for (int it = 0; it < 10; ++it) {
    const int idx = it * 64 + lane;          // 0..639: c2(4) x row(16) x px2(10)
    const int c2  = idx / 160;
    const int rem = idx - c2 * 160;
    const int row = rem / 10;
    const int px2 = rem - row * 10;
    const int ha  = row * 160 + px2 * 16 + c2 * 2;   // half index
    if (c2 < 3) {
      const float* pa = xb + ((size_t)(2 * c2) * IH + (ry0 + row)) * IW + x0 + 2 * px2;
      const float* pb = pa + (size_t)IH * IW;
      const float2 va = *(const float2*)pa;
      const float2 vb = *(const float2*)pb;
      *(unsigned int*)&shw[ha]     = pkh(va.x, vb.x);
      *(unsigned int*)&shw[ha + 8] = pkh(va.y, vb.y);
    } else {  // pad channels 6,7 -> zero
      *(unsigned int*)&shw[ha]     = 0u;
      *(unsigned int*)&shw[ha + 8] = 0u;
    }
  }
  // Wave-level LDS visibility: all 64 lanes' ds_writes complete, no barrier.
  asm volatile("s_waitcnt lgkmcnt(0)" ::: "memory");

  // ---- rolling 6-row A-window, row-pair MFMA ----
  const int voff = (ocl + q) * 8;  // halfs; +32 halfs for m=1 (dx+4)
  f16x8 W6[6][2];
  #pragma unroll
  for (int i = 0; i < 6; ++i) {
    W6[i][0] = *(const f16x8*)&shw[i * 160 + voff];
    W6[i][1] = *(const f16x8*)&shw[i * 160 + voff + 32];
  }

  const size_t obase = ((size_t)b * 16 + ocl) * OH;
  #pragma unroll
  for (int r = 0; r < WROWS; r += 2) {
    f32x4 C0 = {bv, bv, bv, bv};
    f32x4 C1 = {bv, bv, bv, bv};
    #pragma unroll
    for (int dy = 0; dy < 5; ++dy) {
      const int i0 = (r + dy) % 6;       // compile-time after unroll
      const int i1 = (r + 1 + dy) % 6;
      C0 = __builtin_amdgcn_mfma_f32_16x16x32_f16(W6[i0][0], Bf[dy][0], C0, 0, 0, 0);
      C1 = __builtin_amdgcn_mfma_f32_16x16x32_f16(W6[i1][0], Bf[dy][0], C1, 0, 0, 0);
      C0 = __builtin_amdgcn_mfma_f32_16x16x32_f16(W6[i0][1], Bf[dy][1], C0, 0, 0, 0);
      C1 = __builtin_amdgcn_mfma_f32_16x16x32_f16(W6[i1][1], Bf[dy][1], C1, 0, 0, 0);
    }
    if (r + 2 < WROWS) {  // slide window: rows r+6, r+7
      W6[r % 6][0]       = *(const f16x8*)&shw[(r + 6) * 160 + voff];
      W6[r % 6][1]       = *(const f16x8*)&shw[(r + 6) * 160 + voff + 32];
      W6[(r + 1) % 6][0] = *(const f16x8*)&shw[(r + 7) * 160 + voff];
      W6[(r + 1) % 6][1] = *(const f16x8*)&shw[(r + 7) * 160 + voff + 32];
    }
    // store rows r, r+1 (always in-bounds: tiles cover OH/OW exactly)
    {
      float* p0 = out + (obase + (ry0 + r)) * OW + x0 + q * 4;
      float* p1 = out + (obase + (ry0 + r + 1)) * OW + x0 + q * 4;
      *(float2*)p0       = make_float2(act(C0[0]), act(C0[1]));
      *(float2*)(p0 + 2) = make_float2(act(C0[2]), act(C0[3]));
      *(float2*)p1       = make_float2(act(C1[0]), act(C1[1]));
      *(float2*)(p1 + 2) = make_float2(act(C1[2]), act(C1[3]));
    }
  }
}

extern "C" void kernel_launch(void* const* d_in, const int* in_sizes, int n_in,
                              void* d_out, int out_size, void* d_ws, size_t ws_size,
                              hipStream_t stream) {
  const float* x  = (const float*)d_in[0];
  const float* w3 = (const float*)d_in[1];
  const float* b3 = (const float*)d_in[2];
  const float* w4 = (const float*)d_in[3];
  const float* b4 = (const float*)d_in[4];
  const float* w6 = (const float*)d_in[5];
  const float* b6 = (const float*)d_in[6];
  float* out = (float*)d_out;
  _Float16* tab = (_Float16*)d_ws;  // 5120 halfs = 10 KiB

  hipLaunchKernelGGL(wprep_kernel, dim3(20), dim3(256), 0, stream, w3, w4, w6, tab);

  dim3 grid(NTILE_X, NTILE_Y, 256);   // x-tiles (16 px, last shifted), y-tiles (48 rows), batch
  hipLaunchKernelGGL(c3_mfma, grid, dim3(256), 0, stream, x, b3, b4, b6, tab, out);
}

// Round 11
// 162.820 us; speedup vs baseline: 2.2886x; 1.0747x over previous
//
#include <hip/hip_runtime.h>
#include <hip/hip_bf16.h>

// C3 partial connection via MFMA (fp16 in / fp32 acc), wave-independent form.
// y = conv5x5(channel-subsets) + bias; out = 1.7159*tanh(2/3*y).
// M = 16 consecutive x-pixels, N = 16 output channels, K = dx*8 + c (c pad 6->8),
// two mfma_f32_16x16x32_f16 per (row, dy): m=0 dx0..3, m=1 dx4 (rest zero-wt).
//
// R11 = R10 with the staging predicate bug fixed: the active/pad decision is
// PER ITEM (ic2 = (it*64+lane)/160 varies with it AND lane), not per lane.
// R10 used lane/20, writing uninitialized regs into live slots. Loads and
// writes now share the same per-item predicate, mirroring R6 semantics.
// Retained from R10: batched staging (20 loads in flight), 128-thread 2-wave
// blocks, s_setprio around MFMA, chunked XCD swizzle (R9's WRITE-split fix).

#define IH 142
#define IW 142
#define OH 138
#define OW 138
#define WROWS 12        // output rows per wave
#define WSTRIDE 2592    // halfs per wave LDS region: 16 rows * 160 + 32 pad
#define NTILE_X 9
#define NTILE_Y 6
#define NWG (NTILE_X * NTILE_Y * 256)   // 13824, divisible by 8
#define CPX (NWG / 8)                   // 1728 tiles per XCD

typedef _Float16 f16x8 __attribute__((ext_vector_type(8)));
typedef float f32x4 __attribute__((ext_vector_type(4)));

// WIDX[oc][c] = src*64 + block-index, or -1. src 0=w3(6,3,5,5) 1=w4(9,4,5,5)
// 2=w6(1,6,5,5); weight elem = blk*25 + dy*5 + dx.
__device__ __constant__ const short WIDX16[16][6] = {
  {   0,    1,    2,   -1,   -1,   -1},   // oc0  {0,1,2}
  {  -1,    3,    4,    5,   -1,   -1},   // oc1  {1,2,3}
  {  -1,   -1,    6,    7,    8,   -1},   // oc2  {2,3,4}
  {  -1,   -1,   -1,    9,   10,   11},   // oc3  {3,4,5}
  {  12,   -1,   -1,   -1,   13,   14},   // oc4  {0,4,5}
  {  15,   16,   -1,   -1,   -1,   17},   // oc5  {0,1,5}
  {64+0, 64+1, 64+2, 64+3,   -1,   -1},   // oc6  {0,1,2,3}
  {  -1, 64+4, 64+5, 64+6, 64+7,   -1},   // oc7  {1,2,3,4}
  {  -1,   -1, 64+8, 64+9, 64+10, 64+11}, // oc8  {2,3,4,5}
  {64+12,  -1,   -1, 64+13, 64+14, 64+15},// oc9  {0,3,4,5}
  {64+16, 64+17, -1,   -1, 64+18, 64+19}, // oc10 {0,1,4,5}
  {64+20, 64+21, 64+22, -1,  -1, 64+23},  // oc11 {0,1,2,5}
  {64+24, 64+25, -1, 64+26, 64+27,  -1},  // oc12 {0,1,3,4}
  {  -1, 64+28, 64+29, -1, 64+30, 64+31}, // oc13 {1,2,4,5}
  {64+32,  -1, 64+33, 64+34, -1, 64+35},  // oc14 {0,2,3,5}
  {128+0, 128+1, 128+2, 128+3, 128+4, 128+5}, // oc15 {0..5}
};

// prep: per-lane pre-swizzled B fragments, 5 dy x 2 m x 64 lanes x 8 halfs.
__global__ void wprep_kernel(const float* __restrict__ w3, const float* __restrict__ w4,
                             const float* __restrict__ w6, _Float16* __restrict__ tab) {
  int t = blockIdx.x * 256 + threadIdx.x;
  if (t >= 5120) return;
  int j = t & 7, lane = (t >> 3) & 63, dm = t >> 9;
  int dy = dm >> 1, m = dm & 1;
  int q = lane >> 4, oc = lane & 15;
  int k = m * 32 + q * 8 + j;
  int dx = k >> 3, c = k & 7;
  float v = 0.f;
  if (c < 6 && dx < 5) {
    int e = WIDX16[oc][c];
    if (e >= 0) {
      int src = e >> 6, blk = e & 63;
      const float* wp = (src == 0) ? w3 : (src == 1) ? w4 : w6;
      v = wp[blk * 25 + dy * 5 + dx];
    }
  }
  tab[t] = (_Float16)v;
}

__device__ __forceinline__ unsigned int pkh(float a, float b) {
  _Float16 ha = (_Float16)a, hb = (_Float16)b;
  unsigned short ua = __builtin_bit_cast(unsigned short, ha);
  unsigned short ub = __builtin_bit_cast(unsigned short, hb);
  return (unsigned int)ua | ((unsigned int)ub << 16);
}

__device__ __forceinline__ float act(float y) {
  const float TS = 1.9235933878519512f;  // 2*(2/3)*log2(e)
  const float e = __builtin_amdgcn_exp2f(y * TS);
  return fmaf(-2.f * 1.7159f, __builtin_amdgcn_rcpf(e + 1.f), 1.7159f);
}

// Block: 128 threads = 2 independent waves; wave w -> rows y0+w*12..+11, 16 px.
// Logical grid: (9 x-tiles shifted, 6 y-slabs of 24 rows, 256 images),
// XCD-chunk-swizzled from the 1D hardware dispatch order.
__global__ __launch_bounds__(128, 4)
void c3_mfma(const float* __restrict__ x,
             const float* __restrict__ b3, const float* __restrict__ b4,
             const float* __restrict__ b6, const _Float16* __restrict__ tab,
             float* __restrict__ out) {
  __shared__ __attribute__((aligned(16))) _Float16 sh[2 * WSTRIDE];  // 10368 B

  const int tid  = threadIdx.x;
  const int lane = tid & 63;
  const int w    = tid >> 6;   // 0..1

  // ---- chunked XCD swizzle ----
  const int hwid = (int)blockIdx.x + NTILE_X * ((int)blockIdx.y + NTILE_Y * (int)blockIdx.z);
  const int swz  = (hwid & 7) * CPX + (hwid >> 3);
  const int tx   = swz % NTILE_X;
  const int t2   = swz / NTILE_X;
  const int ty   = t2 % NTILE_Y;
  const int b    = t2 / NTILE_Y;

  const int x0   = min(tx * 16, OW - 16);  // {0,16,...,112,122}
  const int y0   = min(ty * 24, OH - 24);  // {0,24,48,72,96,114}
  const int ry0  = y0 + w * WROWS;         // wave's first row

  const int ocl = lane & 15;
  const int q   = lane >> 6 ? 0 : (lane >> 4);  // q = lane>>4 (0..3); keep simple
  // (lane is 0..63 so lane>>6 == 0 always; written plainly below)
  const int qq  = lane >> 4;

  // ---- staging loads FIRST (critical path): all 20 in flight ----
  // Per-ITEM decode: idx = it*64 + lane; ic2 = idx/160 (varies with it AND lane).
  const float* xb = x + (size_t)b * 6 * IH * IW;

  float2 va[10], vb[10];
  int  ha_[10];
  bool act_[10];
  #pragma unroll
  for (int it = 0; it < 10; ++it) {
    const int idx = it * 64 + lane;          // 0..639: ic2(4) x row(16) x px2(10)
    const int ic2 = idx / 160;
    const int rem = idx - ic2 * 160;
    const int row = rem / 10;
    const int px2 = rem - row * 10;
    ha_[it]  = row * 80 + px2 * 8 + ic2;     // dword index in wave LDS region
    act_[it] = (ic2 < 3);
    if (act_[it]) {
      const float* pa = xb + ((size_t)(2 * ic2) * IH + (ry0 + row)) * IW + x0 + 2 * px2;
      va[it] = *(const float2*)pa;
      vb[it] = *(const float2*)(pa + (size_t)IH * IW);
    }
  }

  // ---- B fragments + bias (L2-hot; needed only after staging drains) ----
  f16x8 Bf[5][2];
  #pragma unroll
  for (int dy = 0; dy < 5; ++dy)
    #pragma unroll
    for (int m = 0; m < 2; ++m)
      Bf[dy][m] = *(const f16x8*)(tab + ((size_t)((dy * 2 + m) * 64 + lane)) * 8);

  const float bv = (ocl < 6) ? b3[ocl] : (ocl < 15) ? b4[ocl - 6] : b6[0];

  // ---- pack + ds_write (same per-item predicate as the loads) ----
  _Float16* __restrict__ shw = sh + w * WSTRIDE;
  unsigned int* __restrict__ shu = (unsigned int*)shw;
  if (lane < 16) shu[1280 + lane] = 0u;      // tail pad (m=1 overflow, zero-wt)

  #pragma unroll
  for (int it = 0; it < 10; ++it) {
    if (act_[it]) {
      shu[ha_[it]]     = pkh(va[it].x, vb[it].x);
      shu[ha_[it] + 4] = pkh(va[it].y, vb[it].y);
    } else {                                 // pad channels 6,7 -> zero
      shu[ha_[it]]     = 0u;
      shu[ha_[it] + 4] = 0u;
    }
  }
  // Wave-level LDS visibility: all 64 lanes' ds_writes complete, no barrier.
  asm volatile("s_waitcnt lgkmcnt(0)" ::: "memory");

  // ---- rolling 6-row A-window, row-pair MFMA ----
  const int voff = (ocl + qq) * 8;  // halfs; +32 halfs for m=1 (dx+4)
  f16x8 W6[6][2];
  #pragma unroll
  for (int i = 0; i < 6; ++i) {
    W6[i][0] = *(const f16x8*)&shw[i * 160 + voff];
    W6[i][1] = *(const f16x8*)&shw[i * 160 + voff + 32];
  }

  const size_t obase = ((size_t)b * 16 + ocl) * OH;
  #pragma unroll
  for (int r = 0; r < WROWS; r += 2) {
    f32x4 C0 = {bv, bv, bv, bv};
    f32x4 C1 = {bv, bv, bv, bv};
    __builtin_amdgcn_s_setprio(1);
    #pragma unroll
    for (int dy = 0; dy < 5; ++dy) {
      const int i0 = (r + dy) % 6;       // compile-time after unroll
      const int i1 = (r + 1 + dy) % 6;
      C0 = __builtin_amdgcn_mfma_f32_16x16x32_f16(W6[i0][0], Bf[dy][0], C0, 0, 0, 0);
      C1 = __builtin_amdgcn_mfma_f32_16x16x32_f16(W6[i1][0], Bf[dy][0], C1, 0, 0, 0);
      C0 = __builtin_amdgcn_mfma_f32_16x16x32_f16(W6[i0][1], Bf[dy][1], C0, 0, 0, 0);
      C1 = __builtin_amdgcn_mfma_f32_16x16x32_f16(W6[i1][1], Bf[dy][1], C1, 0, 0, 0);
    }
    __builtin_amdgcn_s_setprio(0);
    if (r + 2 < WROWS) {  // slide window: rows r+6, r+7
      W6[r % 6][0]       = *(const f16x8*)&shw[(r + 6) * 160 + voff];
      W6[r % 6][1]       = *(const f16x8*)&shw[(r + 6) * 160 + voff + 32];
      W6[(r + 1) % 6][0] = *(const f16x8*)&shw[(r + 7) * 160 + voff];
      W6[(r + 1) % 6][1] = *(const f16x8*)&shw[(r + 7) * 160 + voff + 32];
    }
    // store rows r, r+1 (always in-bounds: tiles cover OH/OW exactly)
    {
      float* p0 = out + (obase + (ry0 + r)) * OW + x0 + qq * 4;
      float* p1 = out + (obase + (ry0 + r + 1)) * OW + x0 + qq * 4;
      *(float2*)p0       = make_float2(act(C0[0]), act(C0[1]));
      *(float2*)(p0 + 2) = make_float2(act(C0[2]), act(C0[3]));
      *(float2*)p1       = make_float2(act(C1[0]), act(C1[1]));
      *(float2*)(p1 + 2) = make_float2(act(C1[2]), act(C1[3]));
    }
  }
}

extern "C" void kernel_launch(void* const* d_in, const int* in_sizes, int n_in,
                              void* d_out, int out_size, void* d_ws, size_t ws_size,
                              hipStream_t stream) {
  const float* x  = (const float*)d_in[0];
  const float* w3 = (const float*)d_in[1];
  const float* b3 = (const float*)d_in[2];
  const float* w4 = (const float*)d_in[3];
  const float* b4 = (const float*)d_in[4];
  const float* w6 = (const float*)d_in[5];
  const float* b6 = (const float*)d_in[6];
  float* out = (float*)d_out;
  _Float16* tab = (_Float16*)d_ws;  // 5120 halfs = 10 KiB

  hipLaunchKernelGGL(wprep_kernel, dim3(20), dim3(256), 0, stream, w3, w4, w6, tab);

  dim3 grid(NTILE_X, NTILE_Y, 256);   // x-tiles (16 px), y-slabs (24 rows), batch
  hipLaunchKernelGGL(c3_mfma, grid, dim3(128), 0, stream, x, b3, b4, b6, tab, out);
}